// Round 2
// baseline (1982.494 us; speedup 1.0000x reference)
//
#include <hip/hip_runtime.h>
#include <math.h>

#define B 4
#define NPTS 300000
#define G 15
#define G3 3375
#define KSUB 21                 // partial grids per (b,set) pair
#define PPB 14286               // ceil(300000/21) points per block
#define NPAIR 12                // 3 sets * 4 batches
#define CELLS4 (4*G3)           // 13500 floats per private grid

__device__ __forceinline__ float eluf(float v) {
    return v > 0.0f ? v : __expf(v) - 1.0f;
}

// ---------------------------------------------------------------------------
// Stage 1: per-point MLP + LDS-privatized scatter-max
// mode 0: write partials[pair][sub][13500]  (no global atomics)
// mode 1: global atomicMax directly into scenes (fallback, scenes pre-zeroed)
// ---------------------------------------------------------------------------
__global__ __launch_bounds__(512)
void point_kernel(const float* __restrict__ P0,   // inputs  (set 0)
                  const float* __restrict__ P1,   // goals   (set 1)
                  const float* __restrict__ P2,   // backgrounds (set 2)
                  const float* __restrict__ W1, const float* __restrict__ b1,
                  const float* __restrict__ W2, const float* __restrict__ b2,
                  const float* __restrict__ W3, const float* __restrict__ b3,
                  float* __restrict__ partials, float* __restrict__ scenes,
                  int mode)
{
    __shared__ unsigned gridS[CELLS4];
    __shared__ float sW1T[16*12], sW2T[16*16], sW3T[4*16];
    __shared__ float sb1[16], sb2[16], sb3[4];

    int tid = threadIdx.x;
    for (int i = tid; i < CELLS4; i += 512) gridS[i] = 0u;
    // stage transposed weights: sW?T[j][k]
    for (int i = tid; i < 192; i += 512) { int k = i >> 4, j = i & 15; sW1T[j*12 + k] = W1[i]; }
    for (int i = tid; i < 256; i += 512) { int k = i >> 4, j = i & 15; sW2T[j*16 + k] = W2[i]; }
    for (int i = tid; i < 64;  i += 512) { int k = i >> 2, j = i & 3;  sW3T[j*16 + k] = W3[i]; }
    if (tid < 16) { sb1[tid] = b1[tid]; sb2[tid] = b2[tid]; }
    if (tid < 4)  { sb3[tid] = b3[tid]; }
    __syncthreads();

    int pair = blockIdx.x / KSUB;
    int sub  = blockIdx.x % KSUB;
    int set  = pair >> 2, b = pair & 3;
    const float* P = (set == 0) ? P0 : ((set == 1) ? P1 : P2);
    const float* Pb = P + (size_t)b * NPTS * 3;

    const int start = sub * PPB;
    const int end   = min(NPTS, start + PPB);
    const float HI = 14.9999f;

    for (int base = start; base < end; base += 1024) {
        float xf[2][12];
        int   cell[2];
        bool  act[2];
#pragma unroll
        for (int pp = 0; pp < 2; ++pp) {
            int i = base + pp * 512 + tid;
            act[pp] = (i < end);
            int ii = act[pp] ? i : start;
            float px = Pb[ii*3 + 0], py = Pb[ii*3 + 1], pz = Pb[ii*3 + 2];
            float cx = floorf(fminf(fmaxf(px, 0.0f), HI));
            float cy = floorf(fminf(fmaxf(py, 0.0f), HI));
            float cz = floorf(fminf(fmaxf(pz, 0.0f), HI));
            float* x = xf[pp];
            x[0] = px - (cx + 0.5f); x[1] = py - (cy + 0.5f); x[2] = pz - (cz + 0.5f);
            x[3] = px - cx;          x[4] = py - cy;          x[5] = pz - cz;
            x[6] = px - (cx + 1.0f); x[7] = py - (cy + 1.0f); x[8] = pz - (cz + 1.0f);
            x[9]  = sqrtf(x[0]*x[0] + x[1]*x[1] + x[2]*x[2]);
            x[10] = sqrtf(x[3]*x[3] + x[4]*x[4] + x[5]*x[5]);
            x[11] = sqrtf(x[6]*x[6] + x[7]*x[7] + x[8]*x[8]);
            cell[pp] = (((int)cx) * G + (int)cy) * G + (int)cz;
        }

        float h1[2][16];
#pragma unroll
        for (int j = 0; j < 16; ++j) {
            float4 wa = *(const float4*)&sW1T[j*12 + 0];
            float4 wb = *(const float4*)&sW1T[j*12 + 4];
            float4 wc = *(const float4*)&sW1T[j*12 + 8];
            float bb = sb1[j];
#pragma unroll
            for (int pp = 0; pp < 2; ++pp) {
                const float* x = xf[pp];
                float s = bb;
                s = fmaf(x[0], wa.x, s); s = fmaf(x[1], wa.y, s); s = fmaf(x[2], wa.z, s); s = fmaf(x[3], wa.w, s);
                s = fmaf(x[4], wb.x, s); s = fmaf(x[5], wb.y, s); s = fmaf(x[6], wb.z, s); s = fmaf(x[7], wb.w, s);
                s = fmaf(x[8], wc.x, s); s = fmaf(x[9], wc.y, s); s = fmaf(x[10], wc.z, s); s = fmaf(x[11], wc.w, s);
                h1[pp][j] = eluf(s);
            }
        }
        float h2[2][16];
#pragma unroll
        for (int j = 0; j < 16; ++j) {
            float4 wa = *(const float4*)&sW2T[j*16 + 0];
            float4 wb = *(const float4*)&sW2T[j*16 + 4];
            float4 wc = *(const float4*)&sW2T[j*16 + 8];
            float4 wd = *(const float4*)&sW2T[j*16 + 12];
            float bb = sb2[j];
#pragma unroll
            for (int pp = 0; pp < 2; ++pp) {
                const float* h = h1[pp];
                float s = bb;
                s = fmaf(h[0], wa.x, s); s = fmaf(h[1], wa.y, s); s = fmaf(h[2], wa.z, s); s = fmaf(h[3], wa.w, s);
                s = fmaf(h[4], wb.x, s); s = fmaf(h[5], wb.y, s); s = fmaf(h[6], wb.z, s); s = fmaf(h[7], wb.w, s);
                s = fmaf(h[8], wc.x, s); s = fmaf(h[9], wc.y, s); s = fmaf(h[10], wc.z, s); s = fmaf(h[11], wc.w, s);
                s = fmaf(h[12], wd.x, s); s = fmaf(h[13], wd.y, s); s = fmaf(h[14], wd.z, s); s = fmaf(h[15], wd.w, s);
                h2[pp][j] = eluf(s);
            }
        }
#pragma unroll
        for (int j = 0; j < 4; ++j) {
            float4 wa = *(const float4*)&sW3T[j*16 + 0];
            float4 wb = *(const float4*)&sW3T[j*16 + 4];
            float4 wc = *(const float4*)&sW3T[j*16 + 8];
            float4 wd = *(const float4*)&sW3T[j*16 + 12];
            float bb = sb3[j];
#pragma unroll
            for (int pp = 0; pp < 2; ++pp) {
                const float* h = h2[pp];
                float s = bb;
                s = fmaf(h[0], wa.x, s); s = fmaf(h[1], wa.y, s); s = fmaf(h[2], wa.z, s); s = fmaf(h[3], wa.w, s);
                s = fmaf(h[4], wb.x, s); s = fmaf(h[5], wb.y, s); s = fmaf(h[6], wb.z, s); s = fmaf(h[7], wb.w, s);
                s = fmaf(h[8], wc.x, s); s = fmaf(h[9], wc.y, s); s = fmaf(h[10], wc.z, s); s = fmaf(h[11], wc.w, s);
                s = fmaf(h[12], wd.x, s); s = fmaf(h[13], wd.y, s); s = fmaf(h[14], wd.z, s); s = fmaf(h[15], wd.w, s);
                if (act[pp] && s > 0.0f)
                    atomicMax(&gridS[j*G3 + cell[pp]], __float_as_uint(s));
            }
        }
    }
    __syncthreads();

    if (mode == 0) {
        float* dst = partials + (size_t)(pair * KSUB + sub) * CELLS4;
        for (int i = tid; i < CELLS4; i += 512)
            dst[i] = __uint_as_float(gridS[i]);
    } else {
        float* dst = scenes + (size_t)(b * 12 + set * 4) * G3;
        for (int i = tid; i < CELLS4; i += 512) {
            unsigned v = gridS[i];
            if (v) atomicMax((unsigned*)&dst[i], v);
        }
    }
}

// ---------------------------------------------------------------------------
// Reduce 21 partial grids -> scenes [B,12,G3]
// ---------------------------------------------------------------------------
__global__ __launch_bounds__(256)
void reduce_kernel(const float* __restrict__ partials, float* __restrict__ scenes)
{
    int t = blockIdx.x * 256 + threadIdx.x;
    if (t >= NPAIR * CELLS4) return;          // 162000
    int b   = t / (3 * CELLS4);
    int r   = t % (3 * CELLS4);
    int set = r / CELLS4;
    int r2  = r % CELLS4;
    const float* p = partials + (size_t)(set * 4 + b) * KSUB * CELLS4 + r2;
    float m = 0.0f;
#pragma unroll
    for (int k = 0; k < KSUB; ++k) m = fmaxf(m, p[k * CELLS4]);
    scenes[(size_t)(b * 12 + set * 4) * G3 + r2] = m;
}

// ---------------------------------------------------------------------------
// conv1: scenes [B,12,15,15,15] -> y0 [B,8,8,8,8] (raw conv+bias) + stats0
// grid: (b,co,od)=256 blocks; threads 256 = (ciq,oh,ow); ciq handles 3 ci
// ---------------------------------------------------------------------------
__global__ __launch_bounds__(256)
void conv1_kernel(const float* __restrict__ scenes,
                  const float* __restrict__ w,    // [8,12,125]
                  const float* __restrict__ bias, // [8]
                  float* __restrict__ y, float* __restrict__ stats)
{
    __shared__ float sred[256];
    int bx = blockIdx.x;
    int od = bx & 7, co = (bx >> 3) & 7, b = bx >> 6;
    int tid = threadIdx.x;
    int ow = tid & 7, oh = (tid >> 3) & 7, ciq = tid >> 6;

    float s = 0.0f;
    for (int cin = 0; cin < 3; ++cin) {
        int ci = ciq * 3 + cin;
        const float* sc = scenes + (size_t)(b * 12 + ci) * G3;
        const float* wc = w + (size_t)(co * 12 + ci) * 125;
#pragma unroll
        for (int kd = 0; kd < 5; ++kd) {
            int id = od * 2 - 2 + kd;
            if ((unsigned)id >= (unsigned)G) continue;   // block-uniform
#pragma unroll
            for (int kh = 0; kh < 5; ++kh) {
                int ih = oh * 2 - 2 + kh;
                bool hok = (unsigned)ih < (unsigned)G;
#pragma unroll
                for (int kw = 0; kw < 5; ++kw) {
                    int iw = ow * 2 - 2 + kw;
                    if (hok && (unsigned)iw < (unsigned)G)
                        s = fmaf(sc[(id * G + ih) * G + iw], wc[kd*25 + kh*5 + kw], s);
                }
            }
        }
    }
    sred[tid] = s;
    __syncthreads();
    if (tid < 64) {
        float tot = sred[tid] + sred[64+tid] + sred[128+tid] + sred[192+tid] + bias[co];
        y[(size_t)(b * 8 + co) * 512 + od * 64 + tid] = tot;
        float sum = tot, sq = tot * tot;
#pragma unroll
        for (int o = 32; o > 0; o >>= 1) {
            sum += __shfl_down(sum, o, 64);
            sq  += __shfl_down(sq,  o, 64);
        }
        if (tid == 0) { atomicAdd(&stats[co], sum); atomicAdd(&stats[8 + co], sq); }
    }
}

// ---------------------------------------------------------------------------
// conv_s: BN(stats_in,g,beta)+ELU applied to yin on the fly, then 5^3 conv
// grid: (b,co,od)=256 blocks; 256 threads = (ciq,oh,ow); ciq handles 2 ci
// ---------------------------------------------------------------------------
__global__ __launch_bounds__(256)
void conv_s_kernel(const float* __restrict__ yin,
                   const float* __restrict__ w,     // [8,8,125] this layer
                   const float* __restrict__ bias,  // [8]
                   const float* __restrict__ g, const float* __restrict__ bet,
                   const float* __restrict__ stats_in,
                   float* __restrict__ yout, float* __restrict__ stats_out)
{
    __shared__ float slab[8 * 5 * 144];   // [ci][kd][12][12], zero-padded
    __shared__ float sscale[8], sshift[8];
    __shared__ float sred[256];

    int bx = blockIdx.x;
    int od = bx & 7, co = (bx >> 3) & 7, b = bx >> 6;
    int tid = threadIdx.x;

    if (tid < 8) {
        float S = stats_in[tid], Q = stats_in[8 + tid];
        float m  = S * (1.0f / 2048.0f);
        float vv = Q * (1.0f / 2048.0f) - m * m;
        float rs = rsqrtf(vv + 1e-5f);
        float sc = g[tid] * rs;
        sscale[tid] = sc;
        sshift[tid] = bet[tid] - m * sc;
    }
    __syncthreads();

    for (int s = tid; s < 5760; s += 256) {
        int ci = s / 720; int r = s % 720;
        int kd = r / 144; int r2 = r % 144;
        int ph = r2 / 12, pw = r2 % 12;
        int id = od - 2 + kd, ih = ph - 2, iw = pw - 2;
        float v = 0.0f;
        if ((unsigned)id < 8u && (unsigned)ih < 8u && (unsigned)iw < 8u) {
            float raw = yin[(size_t)(b * 8 + ci) * 512 + id * 64 + ih * 8 + iw];
            float t = fmaf(raw, sscale[ci], sshift[ci]);
            v = t > 0.0f ? t : __expf(t) - 1.0f;
        }
        slab[s] = v;
    }
    __syncthreads();

    int ow = tid & 7, oh = (tid >> 3) & 7, ciq = tid >> 6;
    float s = 0.0f;
#pragma unroll
    for (int c2 = 0; c2 < 2; ++c2) {
        int ci = ciq * 2 + c2;
        const float* sl = slab + ci * 720;
        const float* wc = w + (size_t)(co * 8 + ci) * 125;
#pragma unroll
        for (int kd = 0; kd < 5; ++kd) {
#pragma unroll
            for (int kh = 0; kh < 5; ++kh) {
                const float* row = sl + kd * 144 + (oh + kh) * 12 + ow;
                const float* wr = wc + kd * 25 + kh * 5;
#pragma unroll
                for (int kw = 0; kw < 5; ++kw) s = fmaf(row[kw], wr[kw], s);
            }
        }
    }
    sred[tid] = s;
    __syncthreads();
    if (tid < 64) {
        float tot = sred[tid] + sred[64+tid] + sred[128+tid] + sred[192+tid] + bias[co];
        yout[(size_t)(b * 8 + co) * 512 + od * 64 + tid] = tot;
        float sum = tot, sq = tot * tot;
#pragma unroll
        for (int o = 32; o > 0; o >>= 1) {
            sum += __shfl_down(sum, o, 64);
            sq  += __shfl_down(sq,  o, 64);
        }
        if (tid == 0) { atomicAdd(&stats_out[co], sum); atomicAdd(&stats_out[8 + co], sq); }
    }
}

// ---------------------------------------------------------------------------
// final BN + ELU -> d_out
// ---------------------------------------------------------------------------
__global__ __launch_bounds__(256)
void bn_final_kernel(const float* __restrict__ yin,
                     const float* __restrict__ g, const float* __restrict__ bet,
                     const float* __restrict__ stats_in, float* __restrict__ outp)
{
    int i = blockIdx.x * 256 + threadIdx.x;   // 16384 total
    int c = (i >> 9) & 7;
    float S = stats_in[c], Q = stats_in[8 + c];
    float m  = S * (1.0f / 2048.0f);
    float vv = Q * (1.0f / 2048.0f) - m * m;
    float rs = rsqrtf(vv + 1e-5f);
    float sc = g[c] * rs;
    float sh = bet[c] - m * sc;
    float t = fmaf(yin[i], sc, sh);
    outp[i] = t > 0.0f ? t : __expf(t) - 1.0f;
}

// ---------------------------------------------------------------------------
extern "C" void kernel_launch(void* const* d_in, const int* in_sizes, int n_in,
                              void* d_out, int out_size, void* d_ws, size_t ws_size,
                              hipStream_t stream)
{
    const float* goals       = (const float*)d_in[0];
    const float* inputs      = (const float*)d_in[1];
    const float* backgrounds = (const float*)d_in[2];
    const float* W1 = (const float*)d_in[3];
    const float* b1 = (const float*)d_in[4];
    const float* W2 = (const float*)d_in[5];
    const float* b2 = (const float*)d_in[6];
    const float* W3 = (const float*)d_in[7];
    const float* b3 = (const float*)d_in[8];
    const float* conv1_w = (const float*)d_in[9];
    const float* conv1_b = (const float*)d_in[10];
    const float* bn1_g   = (const float*)d_in[11];
    const float* bn1_b   = (const float*)d_in[12];
    const float* convs_w = (const float*)d_in[13];
    const float* convs_b = (const float*)d_in[14];
    const float* bns_g   = (const float*)d_in[15];
    const float* bns_b   = (const float*)d_in[16];

    const size_t PARTIAL_FLOATS = (size_t)NPAIR * KSUB * CELLS4;   // 3,402,000
    const size_t need = (PARTIAL_FLOATS + 162000 + 2 * 16384 + 112) * sizeof(float);
    bool use_partials = (ws_size >= need);

    float* wsp = (float*)d_ws;
    float *partials, *scenes, *yA, *yB, *stats;
    if (use_partials) {
        partials = wsp;
        scenes   = wsp + PARTIAL_FLOATS;
        yA       = scenes + 162000;
        yB       = yA + 16384;
        stats    = yB + 16384;   // 7 * 16 floats
    } else {
        partials = nullptr;
        scenes   = wsp;
        yA       = scenes + 162000;
        yB       = yA + 16384;
        stats    = yB + 16384;
    }

    hipMemsetAsync(stats, 0, 7 * 16 * sizeof(float), stream);
    if (!use_partials)
        hipMemsetAsync(scenes, 0, 162000 * sizeof(float), stream);

    point_kernel<<<NPAIR * KSUB, 512, 0, stream>>>(
        inputs, goals, backgrounds, W1, b1, W2, b2, W3, b3,
        partials, scenes, use_partials ? 0 : 1);

    if (use_partials) {
        int nthread = NPAIR * CELLS4;  // 162000
        reduce_kernel<<<(nthread + 255) / 256, 256, 0, stream>>>(partials, scenes);
    }

    conv1_kernel<<<256, 256, 0, stream>>>(scenes, conv1_w, conv1_b, yA, stats);

    const float* cur = yA;
    float* nxt = yB;
    for (int i = 0; i < 6; ++i) {
        const float* g   = (i == 0) ? bn1_g : (bns_g + (i - 1) * 8);
        const float* bet = (i == 0) ? bn1_b : (bns_b + (i - 1) * 8);
        conv_s_kernel<<<256, 256, 0, stream>>>(
            cur, convs_w + (size_t)i * 8000, convs_b + i * 8,
            g, bet, stats + i * 16, nxt, stats + (i + 1) * 16);
        const float* tmp = cur; cur = nxt; nxt = (float*)tmp;
    }

    bn_final_kernel<<<64, 256, 0, stream>>>(cur, bns_g + 5 * 8, bns_b + 5 * 8,
                                            stats + 6 * 16, (float*)d_out);
}

// Round 3
// 475.277 us; speedup vs baseline: 4.1712x; 4.1712x over previous
//
#include <hip/hip_runtime.h>
#include <math.h>

#define B 4
#define NPTS 300000
#define G 15
#define G3 3375
#define SCENE_FLOATS (B*12*G3)   // 162000
#define NREP 8

__device__ __forceinline__ float eluf(float v) {
    return v > 0.0f ? v : __expf(v) - 1.0f;
}

// ---------------------------------------------------------------------------
// Stage 1: per-point features -> MLP (weights via uniform/scalar loads) ->
// scatter-max into one of NREP replicated grids (global atomics, low contention)
// grid: (1172, B, 3); block 256
// ---------------------------------------------------------------------------
__global__ __launch_bounds__(256)
void point_kernel(const float* __restrict__ P0,   // inputs  (set 0)
                  const float* __restrict__ P1,   // goals   (set 1)
                  const float* __restrict__ P2,   // backgrounds (set 2)
                  const float* __restrict__ W1, const float* __restrict__ b1,
                  const float* __restrict__ W2, const float* __restrict__ b2,
                  const float* __restrict__ W3, const float* __restrict__ b3,
                  float* __restrict__ scenesR, int nrep)
{
    int b   = blockIdx.y;
    int set = blockIdx.z;
    const float* P = (set == 0) ? P0 : ((set == 1) ? P1 : P2);

    int idx = blockIdx.x * 256 + threadIdx.x;
    if (idx >= NPTS) return;

    const float* p = P + ((size_t)b * NPTS + idx) * 3;
    float px = p[0], py = p[1], pz = p[2];

    const float HI = 14.9999f;  // GZ - 1e-4
    float cx = floorf(fminf(fmaxf(px, 0.0f), HI));
    float cy = floorf(fminf(fmaxf(py, 0.0f), HI));
    float cz = floorf(fminf(fmaxf(pz, 0.0f), HI));

    float x[12];
    x[0] = px - (cx + 0.5f); x[1] = py - (cy + 0.5f); x[2] = pz - (cz + 0.5f);
    x[3] = px - cx;          x[4] = py - cy;          x[5] = pz - cz;
    x[6] = px - (cx + 1.0f); x[7] = py - (cy + 1.0f); x[8] = pz - (cz + 1.0f);
    x[9]  = sqrtf(x[0]*x[0] + x[1]*x[1] + x[2]*x[2]);
    x[10] = sqrtf(x[3]*x[3] + x[4]*x[4] + x[5]*x[5]);
    x[11] = sqrtf(x[6]*x[6] + x[7]*x[7] + x[8]*x[8]);

    // weights are wave-uniform -> compiler emits s_load (constant cache),
    // FMAs take the SGPR operand directly: no LDS traffic at all.
    float h1[16];
#pragma unroll
    for (int j = 0; j < 16; ++j) {
        float s = b1[j];
#pragma unroll
        for (int k = 0; k < 12; ++k) s = fmaf(x[k], W1[k*16 + j], s);
        h1[j] = eluf(s);
    }
    float h2[16];
#pragma unroll
    for (int j = 0; j < 16; ++j) {
        float s = b2[j];
#pragma unroll
        for (int k = 0; k < 16; ++k) s = fmaf(h1[k], W2[k*16 + j], s);
        h2[j] = eluf(s);
    }
    float o[4];
#pragma unroll
    for (int j = 0; j < 4; ++j) {
        float s = b3[j];
#pragma unroll
        for (int k = 0; k < 16; ++k) s = fmaf(h2[k], W3[k*4 + j], s);
        o[j] = s;
    }

    int cell = (((int)cx) * G + (int)cy) * G + (int)cz;
    int rep  = blockIdx.x & (nrep - 1);
    unsigned* dst = (unsigned*)(scenesR + (size_t)rep * SCENE_FLOATS
                                + (size_t)(b * 12 + set * 4) * G3 + cell);
#pragma unroll
    for (int c = 0; c < 4; ++c) {
        float v = o[c];
        if (v > 0.0f)   // grid floor is 0; positive floats order like uints
            atomicMax(dst + c * G3, __float_as_uint(v));
    }
}

// ---------------------------------------------------------------------------
// max-reduce NREP replicated grids -> scenes [B,12,G3]
// ---------------------------------------------------------------------------
__global__ __launch_bounds__(256)
void reduce_kernel(const float* __restrict__ scenesR, float* __restrict__ scenes,
                   int nrep)
{
    int t = blockIdx.x * 256 + threadIdx.x;
    if (t >= SCENE_FLOATS) return;
    float m = 0.0f;
    for (int r = 0; r < nrep; ++r)
        m = fmaxf(m, scenesR[(size_t)r * SCENE_FLOATS + t]);
    scenes[t] = m;
}

// ---------------------------------------------------------------------------
// conv1: scenes [B,12,15,15,15] -> y0 [B,8,8,8,8] (raw conv+bias) + stats0
// grid: (b,co,od)=256 blocks; threads 256 = (ciq,oh,ow); ciq handles 3 ci
// ---------------------------------------------------------------------------
__global__ __launch_bounds__(256)
void conv1_kernel(const float* __restrict__ scenes,
                  const float* __restrict__ w,    // [8,12,125]
                  const float* __restrict__ bias, // [8]
                  float* __restrict__ y, float* __restrict__ stats)
{
    __shared__ float sred[256];
    int bx = blockIdx.x;
    int od = bx & 7, co = (bx >> 3) & 7, b = bx >> 6;
    int tid = threadIdx.x;
    int ow = tid & 7, oh = (tid >> 3) & 7, ciq = tid >> 6;

    float s = 0.0f;
    for (int cin = 0; cin < 3; ++cin) {
        int ci = ciq * 3 + cin;
        const float* sc = scenes + (size_t)(b * 12 + ci) * G3;
        const float* wc = w + (size_t)(co * 12 + ci) * 125;
#pragma unroll
        for (int kd = 0; kd < 5; ++kd) {
            int id = od * 2 - 2 + kd;
            if ((unsigned)id >= (unsigned)G) continue;   // block-uniform
#pragma unroll
            for (int kh = 0; kh < 5; ++kh) {
                int ih = oh * 2 - 2 + kh;
                bool hok = (unsigned)ih < (unsigned)G;
#pragma unroll
                for (int kw = 0; kw < 5; ++kw) {
                    int iw = ow * 2 - 2 + kw;
                    if (hok && (unsigned)iw < (unsigned)G)
                        s = fmaf(sc[(id * G + ih) * G + iw], wc[kd*25 + kh*5 + kw], s);
                }
            }
        }
    }
    sred[tid] = s;
    __syncthreads();
    if (tid < 64) {
        float tot = sred[tid] + sred[64+tid] + sred[128+tid] + sred[192+tid] + bias[co];
        y[(size_t)(b * 8 + co) * 512 + od * 64 + tid] = tot;
        float sum = tot, sq = tot * tot;
#pragma unroll
        for (int o = 32; o > 0; o >>= 1) {
            sum += __shfl_down(sum, o, 64);
            sq  += __shfl_down(sq,  o, 64);
        }
        if (tid == 0) { atomicAdd(&stats[co], sum); atomicAdd(&stats[8 + co], sq); }
    }
}

// ---------------------------------------------------------------------------
// conv_s: BN(stats_in,g,beta)+ELU applied to yin on the fly, then 5^3 conv
// grid: (b,co,od)=256 blocks; 256 threads = (ciq,oh,ow); ciq handles 2 ci
// ---------------------------------------------------------------------------
__global__ __launch_bounds__(256)
void conv_s_kernel(const float* __restrict__ yin,
                   const float* __restrict__ w,     // [8,8,125] this layer
                   const float* __restrict__ bias,  // [8]
                   const float* __restrict__ g, const float* __restrict__ bet,
                   const float* __restrict__ stats_in,
                   float* __restrict__ yout, float* __restrict__ stats_out)
{
    __shared__ float slab[8 * 5 * 144];   // [ci][kd][12][12], zero-padded
    __shared__ float sscale[8], sshift[8];
    __shared__ float sred[256];

    int bx = blockIdx.x;
    int od = bx & 7, co = (bx >> 3) & 7, b = bx >> 6;
    int tid = threadIdx.x;

    if (tid < 8) {
        float S = stats_in[tid], Q = stats_in[8 + tid];
        float m  = S * (1.0f / 2048.0f);
        float vv = Q * (1.0f / 2048.0f) - m * m;
        float rs = rsqrtf(vv + 1e-5f);
        float sc = g[tid] * rs;
        sscale[tid] = sc;
        sshift[tid] = bet[tid] - m * sc;
    }
    __syncthreads();

    for (int s = tid; s < 5760; s += 256) {
        int ci = s / 720; int r = s % 720;
        int kd = r / 144; int r2 = r % 144;
        int ph = r2 / 12, pw = r2 % 12;
        int id = od - 2 + kd, ih = ph - 2, iw = pw - 2;
        float v = 0.0f;
        if ((unsigned)id < 8u && (unsigned)ih < 8u && (unsigned)iw < 8u) {
            float raw = yin[(size_t)(b * 8 + ci) * 512 + id * 64 + ih * 8 + iw];
            float t = fmaf(raw, sscale[ci], sshift[ci]);
            v = t > 0.0f ? t : __expf(t) - 1.0f;
        }
        slab[s] = v;
    }
    __syncthreads();

    int ow = tid & 7, oh = (tid >> 3) & 7, ciq = tid >> 6;
    float s = 0.0f;
#pragma unroll
    for (int c2 = 0; c2 < 2; ++c2) {
        int ci = ciq * 2 + c2;
        const float* sl = slab + ci * 720;
        const float* wc = w + (size_t)(co * 8 + ci) * 125;
#pragma unroll
        for (int kd = 0; kd < 5; ++kd) {
#pragma unroll
            for (int kh = 0; kh < 5; ++kh) {
                const float* row = sl + kd * 144 + (oh + kh) * 12 + ow;
                const float* wr = wc + kd * 25 + kh * 5;
#pragma unroll
                for (int kw = 0; kw < 5; ++kw) s = fmaf(row[kw], wr[kw], s);
            }
        }
    }
    sred[tid] = s;
    __syncthreads();
    if (tid < 64) {
        float tot = sred[tid] + sred[64+tid] + sred[128+tid] + sred[192+tid] + bias[co];
        yout[(size_t)(b * 8 + co) * 512 + od * 64 + tid] = tot;
        float sum = tot, sq = tot * tot;
#pragma unroll
        for (int o = 32; o > 0; o >>= 1) {
            sum += __shfl_down(sum, o, 64);
            sq  += __shfl_down(sq,  o, 64);
        }
        if (tid == 0) { atomicAdd(&stats_out[co], sum); atomicAdd(&stats_out[8 + co], sq); }
    }
}

// ---------------------------------------------------------------------------
// final BN + ELU -> d_out
// ---------------------------------------------------------------------------
__global__ __launch_bounds__(256)
void bn_final_kernel(const float* __restrict__ yin,
                     const float* __restrict__ g, const float* __restrict__ bet,
                     const float* __restrict__ stats_in, float* __restrict__ outp)
{
    int i = blockIdx.x * 256 + threadIdx.x;   // 16384 total
    int c = (i >> 9) & 7;
    float S = stats_in[c], Q = stats_in[8 + c];
    float m  = S * (1.0f / 2048.0f);
    float vv = Q * (1.0f / 2048.0f) - m * m;
    float rs = rsqrtf(vv + 1e-5f);
    float sc = g[c] * rs;
    float sh = bet[c] - m * sc;
    float t = fmaf(yin[i], sc, sh);
    outp[i] = t > 0.0f ? t : __expf(t) - 1.0f;
}

// ---------------------------------------------------------------------------
extern "C" void kernel_launch(void* const* d_in, const int* in_sizes, int n_in,
                              void* d_out, int out_size, void* d_ws, size_t ws_size,
                              hipStream_t stream)
{
    const float* goals       = (const float*)d_in[0];
    const float* inputs      = (const float*)d_in[1];
    const float* backgrounds = (const float*)d_in[2];
    const float* W1 = (const float*)d_in[3];
    const float* b1 = (const float*)d_in[4];
    const float* W2 = (const float*)d_in[5];
    const float* b2 = (const float*)d_in[6];
    const float* W3 = (const float*)d_in[7];
    const float* b3 = (const float*)d_in[8];
    const float* conv1_w = (const float*)d_in[9];
    const float* conv1_b = (const float*)d_in[10];
    const float* bn1_g   = (const float*)d_in[11];
    const float* bn1_b   = (const float*)d_in[12];
    const float* convs_w = (const float*)d_in[13];
    const float* convs_b = (const float*)d_in[14];
    const float* bns_g   = (const float*)d_in[15];
    const float* bns_b   = (const float*)d_in[16];

    // pick replica count by available workspace
    const size_t need8 = (size_t)(NREP * SCENE_FLOATS + SCENE_FLOATS + 2 * 16384 + 112) * 4;
    int nrep = (ws_size >= need8) ? NREP : 1;

    float* wsp     = (float*)d_ws;
    float* scenesR = wsp;                                   // nrep * 162000
    float* scenes  = scenesR + (size_t)nrep * SCENE_FLOATS; // 162000
    float* yA      = scenes + SCENE_FLOATS;                 // 16384
    float* yB      = yA + 16384;                            // 16384
    float* stats   = yB + 16384;                            // 7*16 floats

    hipMemsetAsync(scenesR, 0, (size_t)nrep * SCENE_FLOATS * sizeof(float), stream);
    hipMemsetAsync(stats, 0, 7 * 16 * sizeof(float), stream);

    dim3 pgrid((NPTS + 255) / 256, B, 3);
    point_kernel<<<pgrid, 256, 0, stream>>>(inputs, goals, backgrounds,
                                            W1, b1, W2, b2, W3, b3, scenesR, nrep);

    reduce_kernel<<<(SCENE_FLOATS + 255) / 256, 256, 0, stream>>>(scenesR, scenes, nrep);

    conv1_kernel<<<256, 256, 0, stream>>>(scenes, conv1_w, conv1_b, yA, stats);

    const float* cur = yA;
    float* nxt = yB;
    for (int i = 0; i < 6; ++i) {
        const float* g   = (i == 0) ? bn1_g : (bns_g + (i - 1) * 8);
        const float* bet = (i == 0) ? bn1_b : (bns_b + (i - 1) * 8);
        conv_s_kernel<<<256, 256, 0, stream>>>(
            cur, convs_w + (size_t)i * 8000, convs_b + i * 8,
            g, bet, stats + i * 16, nxt, stats + (i + 1) * 16);
        const float* tmp = cur; cur = nxt; nxt = (float*)tmp;
    }

    bn_final_kernel<<<64, 256, 0, stream>>>(cur, bns_g + 5 * 8, bns_b + 5 * 8,
                                            stats + 6 * 16, (float*)d_out);
}